// Round 13
// baseline (4103.978 us; speedup 1.0000x reference)
//
#include <hip/hip_runtime.h>
#include <cstdint>
#include <cstddef>

#define S_LEN 512
#define NB    64
#define NI    1024
#define NH    1024
#define NR    4096   // 4 gates * NH, interleaved r = j*4 + g  (g: 0=i,1=f,2=c,3=o)
#define NGRP  4      // independent batch groups (16 batches each)
#define WPG   64     // WGs per group; each WG owns 64 weight rows = 16 j
#define BPG   16     // batches per group
#define HSLOT 33792  // per-step h slot: [wq=64][b=16][jl=16] bf16 (32 KB) + 1 KB pad
#define FLAGSTRIDE 16   // dwords between barrier flags (64 B)
#define P_AHEAD 8    // gx register-ring depth (produce gx[t+8] at step t)

typedef short bf16x8 __attribute__((ext_vector_type(8)));
typedef float f32x4  __attribute__((ext_vector_type(4)));

__device__ __forceinline__ short f2bf(float f) {
  uint32_t u = __float_as_uint(f);
  u += 0x7fff + ((u >> 16) & 1);          // RNE
  return (short)(u >> 16);
}
__device__ __forceinline__ float bf2f(short s) {
  return __uint_as_float(((uint32_t)(uint16_t)s) << 16);
}
__device__ __forceinline__ void gload16(const void* g, void* l) {
  __builtin_amdgcn_global_load_lds((const __attribute__((address_space(1))) void*)g,
                                   (__attribute__((address_space(3))) void*)l, 16, 0, 0);
}
__device__ __forceinline__ float sigm(float x) { return 1.0f / (1.0f + __expf(-x)); }
__device__ __forceinline__ float tanh_fast(float x) {
  return 2.0f / (1.0f + __expf(-2.0f * x)) - 1.0f;
}

// fabric write-through / uncached read (no fences needed; r3-r12 proven)
__device__ __forceinline__ void astore32(void* p, uint32_t v) {
  __hip_atomic_store((uint32_t*)p, v, __ATOMIC_RELAXED, __HIP_MEMORY_SCOPE_AGENT);
}
__device__ __forceinline__ void astore16(void* p, uint16_t v) {
  __hip_atomic_store((uint16_t*)p, v, __ATOMIC_RELAXED, __HIP_MEMORY_SCOPE_AGENT);
}
__device__ __forceinline__ uint32_t aload32(const void* p) {
  return __hip_atomic_load((const uint32_t*)p, __ATOMIC_RELAXED, __HIP_MEMORY_SCOPE_AGENT);
}

// ---------------- prep kernels ----------------

__global__ __launch_bounds__(256) void k_convert_x(const float* __restrict__ x,
                                                   short* __restrict__ xbf) {
  int tid = blockIdx.x * 256 + threadIdx.x;        // exactly SB*NI/4 threads
  float4 v = ((const float4*)x)[tid];
  short4 o;
  o.x = f2bf(v.x); o.y = f2bf(v.y); o.z = f2bf(v.z); o.w = f2bf(v.w);
  ((short4*)xbf)[tid] = o;
}

struct WPtrs { const float *xi, *xf, *xc, *xo, *hi, *hf, *hc, *ho; };

__global__ __launch_bounds__(256) void k_pack_w(WPtrs w, short* __restrict__ wxcat,
                                                short* __restrict__ whcat) {
  int tid  = blockIdx.x * 256 + threadIdx.x;       // NR*NI/4 threads
  int flat = tid * 4;
  int r = flat >> 10, k = flat & 1023;
  int j = r >> 2, g = r & 3;
  const float* px = (g == 0) ? w.xi : (g == 1) ? w.xf : (g == 2) ? w.xc : w.xo;
  const float* ph = (g == 0) ? w.hi : (g == 1) ? w.hf : (g == 2) ? w.hc : w.ho;
  float4 vx = *(const float4*)(px + j * 1024 + k);
  float4 vh = *(const float4*)(ph + j * 1024 + k);
  short4 ox, oh;
  ox.x = f2bf(vx.x); ox.y = f2bf(vx.y); ox.z = f2bf(vx.z); ox.w = f2bf(vx.w);
  oh.x = f2bf(vh.x); oh.y = f2bf(vh.y); oh.z = f2bf(vh.z); oh.w = f2bf(vh.w);
  *(short4*)(wxcat + flat) = ox;
  *(short4*)(whcat + flat) = oh;
}

struct BPtrs { const float *xi,*hi,*i_, *xf,*hf,*f_, *xc,*hc,*c_, *xo,*ho,*o_; };

__global__ __launch_bounds__(256) void k_init(BPtrs p, float* __restrict__ bias,
                                              unsigned int* __restrict__ flags) {
  int tid = blockIdx.x * 256 + threadIdx.x;        // NR = 4096 threads
  flags[tid] = 0;                                  // 4 grp x 64 wg x 16 = 4096 flags
  int j = tid >> 2, g = tid & 3;
  const float* bx = (g == 0) ? p.xi : (g == 1) ? p.xf : (g == 2) ? p.xc : p.xo;
  const float* bh = (g == 0) ? p.hi : (g == 1) ? p.hf : (g == 2) ? p.hc : p.ho;
  const float* bb = (g == 0) ? p.i_ : (g == 1) ? p.f_ : (g == 2) ? p.c_ : p.o_;
  bias[tid] = bx[j] + bh[j] + bb[j];
}

// ---------------- fused persistent kernel: recurrence + in-register gx GEMM --------
// 256 WGs x 256 threads, 1 WG/CU. Group g = blockIdx&3 owns batches [g*16,+16);
// WG wq = blockIdx>>2 owns weight rows [wq*64,+64) == j in [wq*16,+16).
// The gx tile this WG consumes == the tile it can produce itself: Wx rows
// pinned in 128 VGPRs; each step, in the poll window (dead time), one quantum
// x[t+8] x Wx^T -> register ring gxr[8] (static-indexed shift, rule #20).
// gx NEVER touches memory (-268 MB write, -268 MB read, -gemm dispatch).
// SWAPPED MFMA everywhere (r11-verified): C[r][b] puts the 4 gates of (b,jl)
// in one lane's acc[0..3]; producer lane == consumer lane. Bias added in f32
// at pointwise. h exchange protocol = r10/r12 (rotating slots + flag array,
// proven under replay). Only cross-WG protocol is h; production is intra-WG.
// x-frag loads issue AFTER the flag store (younger than everything the drain
// waits on -> never gate a[] consumption; r7 in-order-vmcnt lesson).
//
// LDS: Wh 64rows x 1024k bf16 (2048-B rows, XOR-swz). Nothing else.
#define LDS_BYTES 131072

__global__ __launch_bounds__(256, 1) void lstm_persist(
    const short* __restrict__ xbf,  // [S][64][1024] bf16
    const short* __restrict__ wx,   // [4096][1024] gate-interleaved
    const short* __restrict__ wh,   // [4096][1024]
    const float* __restrict__ bias, // [4096]
    char* __restrict__ hb,          // rotating h slots: [grp][S][HSLOT]
    unsigned int* __restrict__ flags, // [NGRP][WPG*FLAGSTRIDE]
    float* __restrict__ out) {
  extern __shared__ __align__(16) char lds[];
  char* WhC = lds;

  const int tid = threadIdx.x, wave = tid >> 6, lane = tid & 63;
  const int grp = blockIdx.x & 3;
  const int wq  = blockIdx.x >> 2;
  const int r0  = wq * 64;          // first weight row
  const int j0  = wq * 16;          // first hidden unit
  const char* whB = (const char*)(wh + (size_t)r0 * NH);
  char* hb_g = hb + (size_t)grp * S_LEN * HSLOT;
  unsigned int* flags_g = flags + grp * WPG * FLAGSTRIDE;

  // ---- stage Wh into LDS (64 rows x 2 KB), pre-swizzled source (rule #21) ----
#pragma unroll
  for (int p = 0; p < 32; ++p) {
    int L = p * 4096 + tid * 16;
    int row = L >> 11, kb = L & 2047;
    gload16(whB + (size_t)row * 2048 + (kb ^ ((row & 7) << 4)), lds + L);
  }

  // lane identity (r11-verified): batch b_ln, unit jl; acc[q] = gate q
  const int b_ln = lane & 15;
  const int jl   = wave * 4 + (lane >> 4);
  const int arow = wave * 16 + (lane & 15);   // A-operand row (both GEMMs)
  float c_reg = 0.f;

  // Wx rows pinned in registers: wxr[ks] = Wx[r0+arow][ks*32 + (lane>>4)*8 ..+8]
  bf16x8 wxr[32];
  {
    const short* wxp = wx + (size_t)(r0 + arow) * NI + (lane >> 4) * 8;
#pragma unroll
    for (int ks = 0; ks < 32; ++ks)
      wxr[ks] = *(const bf16x8*)(wxp + ks * 32);
  }

  // h (B-operand) fragment offset into [wq_k][b][jl] slot layout (r11-verified)
  const int aoff = (lane >> 5) * 512 + (lane & 15) * 32 + ((lane >> 4) & 1) * 16;
  // Wh (A-operand) LDS fragment
  const int bswz = (arow & 7) << 4;
  const int bcol = (lane >> 4) * 16;
  // x (B-operand) fragment base: xbf[t'][grp*16 + (lane&15)][ks*32 + (lane>>4)*8]
  const short* xme = xbf + ((size_t)grp * BPG + (lane & 15)) * NI + (lane >> 4) * 8;

  const f32x4 bias_r = *(const f32x4*)(bias + (j0 + jl) * 4);

  const unsigned int* fpoll = flags_g + lane * FLAGSTRIDE;
  char*  h_me   = hb_g + wq * 512 + b_ln * 32 + jl * 2;
  float* out_me = out + (size_t)(grp * BPG + b_ln) * NH + j0 + jl;

  __syncthreads();   // Wh resident (vmcnt drained by compiler before barrier)

  // ---- prologue: produce gx[0..P) into the register ring ----
  uint2 gxr[P_AHEAD];
#pragma unroll
  for (int p = 0; p < P_AHEAD; ++p) {
    const short* xs = xme + (size_t)p * NB * NI;
    bf16x8 xb[32];
#pragma unroll
    for (int ks = 0; ks < 32; ++ks)
      xb[ks] = *(const bf16x8*)(xs + ks * 32);
    f32x4 g0 = {}, g1 = {};
#pragma unroll
    for (int ks = 0; ks < 32; ++ks) {
      if (ks & 1) g1 = __builtin_amdgcn_mfma_f32_16x16x32_bf16(wxr[ks], xb[ks], g1, 0, 0, 0);
      else        g0 = __builtin_amdgcn_mfma_f32_16x16x32_bf16(wxr[ks], xb[ks], g0, 0, 0, 0);
    }
    f32x4 gs = g0 + g1;
    gxr[p].x = (uint32_t)(uint16_t)f2bf(gs[0]) | ((uint32_t)(uint16_t)f2bf(gs[1]) << 16);
    gxr[p].y = (uint32_t)(uint16_t)f2bf(gs[2]) | ((uint32_t)(uint16_t)f2bf(gs[3]) << 16);
  }

  for (int t = 0; t < S_LEN; ++t) {
    // ---- h matvec (swapped): acc[q] = gate q pre-activation of (b_ln, j0+jl) ----
    f32x4 acc0 = {}, acc1 = {};
    if (t) {
      const char* hs = hb_g + (size_t)(t - 1) * HSLOT + aoff;
      bf16x8 a[32];
#pragma unroll
      for (int ks = 0; ks < 32; ++ks)          // one parallel miss wave (512-VGPR budget)
        a[ks] = *(const bf16x8*)(hs + ks * 1024);
      __builtin_amdgcn_sched_barrier(0);
#pragma unroll
      for (int ks = 0; ks < 32; ++ks) {
        int wb = ks * 64 + bcol;
        bf16x8 w0 = *(const bf16x8*)(WhC + arow * 2048 + (wb ^ bswz));
        if (ks & 1) acc1 = __builtin_amdgcn_mfma_f32_16x16x32_bf16(w0, a[ks], acc1, 0, 0, 0);
        else        acc0 = __builtin_amdgcn_mfma_f32_16x16x32_bf16(w0, a[ks], acc0, 0, 0, 0);
      }
    }

    // ---- lane-local pointwise (gx from register ring, bias in f32) ----
    f32x4 ah = acc0 + acc1;
    float vi = ah[0] + bf2f((short)(gxr[0].x & 0xffff))  + bias_r[0];
    float vf = ah[1] + bf2f((short)(gxr[0].x >> 16))     + bias_r[1];
    float vg = ah[2] + bf2f((short)(gxr[0].y & 0xffff))  + bias_r[2];
    float vo = ah[3] + bf2f((short)(gxr[0].y >> 16))     + bias_r[3];
    float ig = sigm(vi), fg = sigm(vf), gg = tanh_fast(vg), og = sigm(vo);
    c_reg = fg * c_reg + ig * gg;
    float hn = og * tanh_fast(c_reg);

    // shift ring (full unroll -> static indices, rule #20)
#pragma unroll
    for (int i = 0; i < P_AHEAD - 1; ++i) gxr[i] = gxr[i + 1];

    // ---- publish h (write-through, 2 B) + out store (cached) ----
    if (t != S_LEN - 1)
      astore16(h_me + (size_t)t * HSLOT, (uint16_t)f2bf(hn));
    out_me[(size_t)t * NB * NH] = hn;
    if (t == S_LEN - 1) {
      float* oh = out + (size_t)S_LEN * NB * NH;
      size_t ci = (size_t)(grp * BPG + b_ln) * NH + j0 + jl;
      oh[ci] = hn;                        // final h
      oh[(size_t)NB * NH + ci] = c_reg;   // final c
    }

    if (t != S_LEN - 1) {
      __syncthreads();   // FULL drain: h + out stores acked at coherence point
      const unsigned want = (unsigned)(t + 1);
      if (tid == 0) astore32((void*)(flags_g + wq * FLAGSTRIDE), want);

      // ---- production quantum for t+P, hidden in the poll window ----
      if (t + P_AHEAD < S_LEN) {
        const short* xs = xme + (size_t)(t + P_AHEAD) * NB * NI;
        bf16x8 xb[32];
#pragma unroll
        for (int ks = 0; ks < 32; ++ks)
          xb[ks] = *(const bf16x8*)(xs + ks * 32);
        f32x4 g0 = {}, g1 = {};
#pragma unroll
        for (int ks = 0; ks < 32; ++ks) {
          if (ks & 1) g1 = __builtin_amdgcn_mfma_f32_16x16x32_bf16(wxr[ks], xb[ks], g1, 0, 0, 0);
          else        g0 = __builtin_amdgcn_mfma_f32_16x16x32_bf16(wxr[ks], xb[ks], g0, 0, 0, 0);
        }
        f32x4 gs = g0 + g1;
        gxr[P_AHEAD - 1].x = (uint32_t)(uint16_t)f2bf(gs[0]) | ((uint32_t)(uint16_t)f2bf(gs[1]) << 16);
        gxr[P_AHEAD - 1].y = (uint32_t)(uint16_t)f2bf(gs[2]) | ((uint32_t)(uint16_t)f2bf(gs[3]) << 16);
      }

      if (wave == 0) {
        uint32_t v = aload32(fpoll);
        while (!__all(v >= want)) {
          __builtin_amdgcn_s_sleep(1);
          v = aload32(fpoll);
        }
      }
      __syncthreads();   // release: h slot t visible & fresh for everyone
    }
  }
}

// ---------------- launch ----------------

extern "C" void kernel_launch(void* const* d_in, const int* in_sizes, int n_in,
                              void* d_out, int out_size, void* d_ws, size_t ws_size,
                              hipStream_t stream) {
  const float* x   = (const float*)d_in[0];
  const float* wxi = (const float*)d_in[1];
  const float* bxi = (const float*)d_in[2];
  const float* whi = (const float*)d_in[3];
  const float* bhi = (const float*)d_in[4];
  const float* bi  = (const float*)d_in[5];
  const float* wxf = (const float*)d_in[6];
  const float* bxf = (const float*)d_in[7];
  const float* whf = (const float*)d_in[8];
  const float* bhf = (const float*)d_in[9];
  const float* bf  = (const float*)d_in[10];
  const float* wxc = (const float*)d_in[11];
  const float* bxc = (const float*)d_in[12];
  const float* whc = (const float*)d_in[13];
  const float* bhc = (const float*)d_in[14];
  const float* bc  = (const float*)d_in[15];
  const float* wxo = (const float*)d_in[16];
  const float* bxo = (const float*)d_in[17];
  const float* who = (const float*)d_in[18];
  const float* bho = (const float*)d_in[19];
  const float* bo  = (const float*)d_in[20];

  char* ws = (char*)d_ws;
  const size_t SB = (size_t)S_LEN * NB;
  size_t off = 0;
  short* xbf   = (short*)(ws + off); off += SB * NI * 2;          // 67 MB (LIVE all run)
  short* wxcat = (short*)(ws + off); off += (size_t)NR * NI * 2;  // 8 MB
  short* whcat = (short*)(ws + off); off += (size_t)NR * NH * 2;  // 8 MB
  float* bias  = (float*)(ws + off); off += NR * 4;
  unsigned int* flags = (unsigned int*)(ws + off); off += NGRP * WPG * FLAGSTRIDE * 4;
  char* hb     = ws + off; off += (size_t)NGRP * S_LEN * HSLOT;   // 69 MB
  (void)ws_size; (void)in_sizes; (void)n_in; (void)out_size;

  float* out = (float*)d_out;

  (void)hipFuncSetAttribute((const void*)lstm_persist,
                            hipFuncAttributeMaxDynamicSharedMemorySize, LDS_BYTES);

  k_convert_x<<<(int)(SB * NI / 4 / 256), 256, 0, stream>>>(x, xbf);
  WPtrs wp = {wxi, wxf, wxc, wxo, whi, whf, whc, who};
  k_pack_w<<<(NR * NI / 4) / 256, 256, 0, stream>>>(wp, wxcat, whcat);
  BPtrs bp = {bxi, bhi, bi, bxf, bhf, bf, bxc, bhc, bc, bxo, bho, bo};
  k_init<<<NR / 256, 256, 0, stream>>>(bp, bias, flags);

  lstm_persist<<<NGRP * WPG, 256, LDS_BYTES, stream>>>(xbf, wxcat, whcat, bias,
                                                       hb, flags, out);
}

// Round 14
// 2401.654 us; speedup vs baseline: 1.7088x; 1.7088x over previous
//
#include <hip/hip_runtime.h>
#include <cstdint>
#include <cstddef>

#define S_LEN 512
#define NB    64
#define NI    1024
#define NH    1024
#define NR    4096   // 4 gates * NH, interleaved r = j*4 + g  (g: 0=i,1=f,2=c,3=o)
#define NGRP  4      // independent batch groups (16 batches each)
#define WPG   64     // WGs per group; each WG owns 64 weight rows = 16 j
#define BPG   16     // batches per group
#define HSLOT 33792  // per-step h slot: [wq=64][b=16][jl=16] bf16 (32 KB) + 1 KB pad
#define FLAGSTRIDE 16   // dwords between barrier flags (64 B)

typedef short bf16x8 __attribute__((ext_vector_type(8)));
typedef float f32x4  __attribute__((ext_vector_type(4)));

__device__ __forceinline__ short f2bf(float f) {
  uint32_t u = __float_as_uint(f);
  u += 0x7fff + ((u >> 16) & 1);          // RNE
  return (short)(u >> 16);
}
__device__ __forceinline__ float bf2f(short s) {
  return __uint_as_float(((uint32_t)(uint16_t)s) << 16);
}
__device__ __forceinline__ void gload16(const void* g, void* l) {
  __builtin_amdgcn_global_load_lds((const __attribute__((address_space(1))) void*)g,
                                   (__attribute__((address_space(3))) void*)l, 16, 0, 0);
}
__device__ __forceinline__ float sigm(float x) { return 1.0f / (1.0f + __expf(-x)); }
__device__ __forceinline__ float tanh_fast(float x) {
  return 2.0f / (1.0f + __expf(-2.0f * x)) - 1.0f;
}

// fabric write-through / uncached read (no fences needed; r3-r12 proven)
__device__ __forceinline__ void astore32(void* p, uint32_t v) {
  __hip_atomic_store((uint32_t*)p, v, __ATOMIC_RELAXED, __HIP_MEMORY_SCOPE_AGENT);
}
__device__ __forceinline__ void astore16(void* p, uint16_t v) {
  __hip_atomic_store((uint16_t*)p, v, __ATOMIC_RELAXED, __HIP_MEMORY_SCOPE_AGENT);
}
__device__ __forceinline__ uint32_t aload32(const void* p) {
  return __hip_atomic_load((const uint32_t*)p, __ATOMIC_RELAXED, __HIP_MEMORY_SCOPE_AGENT);
}

// ---------------- prep kernels ----------------

__global__ __launch_bounds__(256) void k_convert_x(const float* __restrict__ x,
                                                   short* __restrict__ xbf) {
  int tid = blockIdx.x * 256 + threadIdx.x;        // exactly SB*NI/4 threads
  float4 v = ((const float4*)x)[tid];
  short4 o;
  o.x = f2bf(v.x); o.y = f2bf(v.y); o.z = f2bf(v.z); o.w = f2bf(v.w);
  ((short4*)xbf)[tid] = o;
}

struct WPtrs { const float *xi, *xf, *xc, *xo, *hi, *hf, *hc, *ho; };

__global__ __launch_bounds__(256) void k_pack_w(WPtrs w, short* __restrict__ wxcat,
                                                short* __restrict__ whcat) {
  int tid  = blockIdx.x * 256 + threadIdx.x;       // NR*NI/4 threads
  int flat = tid * 4;
  int r = flat >> 10, k = flat & 1023;
  int j = r >> 2, g = r & 3;
  const float* px = (g == 0) ? w.xi : (g == 1) ? w.xf : (g == 2) ? w.xc : w.xo;
  const float* ph = (g == 0) ? w.hi : (g == 1) ? w.hf : (g == 2) ? w.hc : w.ho;
  float4 vx = *(const float4*)(px + j * 1024 + k);
  float4 vh = *(const float4*)(ph + j * 1024 + k);
  short4 ox, oh;
  ox.x = f2bf(vx.x); ox.y = f2bf(vx.y); ox.z = f2bf(vx.z); ox.w = f2bf(vx.w);
  oh.x = f2bf(vh.x); oh.y = f2bf(vh.y); oh.z = f2bf(vh.z); oh.w = f2bf(vh.w);
  *(short4*)(wxcat + flat) = ox;
  *(short4*)(whcat + flat) = oh;
}

struct BPtrs { const float *xi,*hi,*i_, *xf,*hf,*f_, *xc,*hc,*c_, *xo,*ho,*o_; };

__global__ __launch_bounds__(256) void k_init(BPtrs p, float* __restrict__ bias,
                                              unsigned int* __restrict__ flags) {
  int tid = blockIdx.x * 256 + threadIdx.x;        // NR = 4096 threads
  flags[tid] = 0;                                  // 4 grp x 64 wg x 16 = 4096 flags
  int j = tid >> 2, g = tid & 3;
  const float* bx = (g == 0) ? p.xi : (g == 1) ? p.xf : (g == 2) ? p.xc : p.xo;
  const float* bh = (g == 0) ? p.hi : (g == 1) ? p.hf : (g == 2) ? p.hc : p.ho;
  const float* bb = (g == 0) ? p.i_ : (g == 1) ? p.f_ : (g == 2) ? p.c_ : p.o_;
  bias[tid] = bx[j] + bh[j] + bb[j];
}

// ---------------- fused persistent kernel: recurrence + in-LDS-fed gx production ------
// 256 WGs x 256 threads, 1 WG/CU. Group g = blockIdx&3 owns batches [g*16,+16);
// WG wq = blockIdx>>2 owns weight rows [wq*64,+64) == j in [wq*16,+16).
// gx never touches global memory: Wx rows pinned in 128 VGPRs; x[t+1] tile
// (16b x 1024k = 32 KB) staged into spare LDS via global_load_lds at step top
// (drained by the pre-flag sync); production quantum (32 swizzled ds_read_b128
// + 32 MFMA) runs in the poll shadow -> gx for t+1 in a 2-entry register ring.
// r13's failure (VGPR-serialized x global loads) is structurally removed: x
// fragments come from LDS. SWAPPED MFMA (r11/r13-verified): lane owns all 4
// gates of (b_ln, j0+jl); producer lane == consumer lane. Bias in f32.
// h protocol = r10/r12 verbatim (rotating slots + flag array).
// Race audit: xstage overwrite (top of t+1) fenced by t's release-sync
// (lgkmcnt drain => production ds_reads retired); production read of tile t+1
// fenced by t's drain-sync (vmcnt(0) => gloads landed).
//
// LDS: [0,131072) Wh 64r x 1024k bf16 (2048-B rows, XOR-swz);
//      [131072,163840) xstage 16b x 1024k bf16 (2048-B rows, XOR-swz).
#define LDS_BYTES 163840
#define XS_OFF    131072

__global__ __launch_bounds__(256, 1) void lstm_persist(
    const short* __restrict__ xbf,  // [S][64][1024] bf16
    const short* __restrict__ wx,   // [4096][1024] gate-interleaved
    const short* __restrict__ wh,   // [4096][1024]
    const float* __restrict__ bias, // [4096]
    char* __restrict__ hb,          // rotating h slots: [grp][S][HSLOT]
    unsigned int* __restrict__ flags, // [NGRP][WPG*FLAGSTRIDE]
    float* __restrict__ out) {
  extern __shared__ __align__(16) char lds[];
  char* WhC = lds;
  char* XsC = lds + XS_OFF;

  const int tid = threadIdx.x, wave = tid >> 6, lane = tid & 63;
  const int grp = blockIdx.x & 3;
  const int wq  = blockIdx.x >> 2;
  const int r0  = wq * 64;          // first weight row
  const int j0  = wq * 16;          // first hidden unit
  const char* whB = (const char*)(wh + (size_t)r0 * NH);
  char* hb_g = hb + (size_t)grp * S_LEN * HSLOT;
  unsigned int* flags_g = flags + grp * WPG * FLAGSTRIDE;

  // x tile base for this group (bytes); tile t' starts at xgB + t'*NB*NI*2
  const char* xgB = (const char*)(xbf + (size_t)grp * BPG * NI);

  // stage x[t'] tile into XsC: 8 gload16/thread, pre-swizzled source (rule #21)
  auto stage_x = [&](int tp) {
    const char* src = xgB + (size_t)tp * NB * NI * 2;
#pragma unroll
    for (int p = 0; p < 8; ++p) {
      int L = p * 4096 + tid * 16;
      int row = L >> 11, kb = L & 2047;
      gload16(src + (size_t)row * 2048 + (kb ^ ((row & 7) << 4)), XsC + L);
    }
  };

  // ---- stage Wh into LDS (64 rows x 2 KB), pre-swizzled source ----
#pragma unroll
  for (int p = 0; p < 32; ++p) {
    int L = p * 4096 + tid * 16;
    int row = L >> 11, kb = L & 2047;
    gload16(whB + (size_t)row * 2048 + (kb ^ ((row & 7) << 4)), lds + L);
  }
  stage_x(0);   // x[0] for the prologue production

  // lane identity (r11/r13-verified): batch b_ln, unit jl; acc[q] = gate q
  const int b_ln = lane & 15;
  const int jl   = wave * 4 + (lane >> 4);
  const int arow = wave * 16 + (lane & 15);   // A-operand row (both GEMMs)
  float c_reg = 0.f;

  // Wx rows pinned in registers (r13-verified mapping)
  bf16x8 wxr[32];
  {
    const short* wxp = wx + (size_t)(r0 + arow) * NI + (lane >> 4) * 8;
#pragma unroll
    for (int ks = 0; ks < 32; ++ks)
      wxr[ks] = *(const bf16x8*)(wxp + ks * 32);
  }

  // h (B-operand) fragment offset into [wq_k][b][jl] slot layout (r10-verified)
  const int aoff = (lane >> 5) * 512 + (lane & 15) * 32 + ((lane >> 4) & 1) * 16;
  // Wh (A-operand) LDS fragment
  const int bswz = (arow & 7) << 4;
  const int bcol = (lane >> 4) * 16;
  // x (B-operand) LDS fragment: row = lane&15 (2048-B rows, same swz as Wh)
  const int xrow = lane & 15;
  const int xswz = (xrow & 7) << 4;

  const f32x4 bias_r = *(const f32x4*)(bias + (j0 + jl) * 4);

  const unsigned int* fpoll = flags_g + lane * FLAGSTRIDE;
  char*  h_me   = hb_g + wq * 512 + b_ln * 32 + jl * 2;
  float* out_me = out + (size_t)(grp * BPG + b_ln) * NH + j0 + jl;

  // production quantum: gx tile from XsC (swizzled ds_reads) x wxr -> 2 dwords
  auto produce = [&](uint2& dst) {
    f32x4 g0 = {}, g1 = {};
#pragma unroll
    for (int ks = 0; ks < 32; ++ks) {
      int xb_off = ks * 64 + bcol;
      bf16x8 xb = *(const bf16x8*)(XsC + xrow * 2048 + (xb_off ^ xswz));
      if (ks & 1) g1 = __builtin_amdgcn_mfma_f32_16x16x32_bf16(wxr[ks], xb, g1, 0, 0, 0);
      else        g0 = __builtin_amdgcn_mfma_f32_16x16x32_bf16(wxr[ks], xb, g0, 0, 0, 0);
    }
    f32x4 gs = g0 + g1;
    dst.x = (uint32_t)(uint16_t)f2bf(gs[0]) | ((uint32_t)(uint16_t)f2bf(gs[1]) << 16);
    dst.y = (uint32_t)(uint16_t)f2bf(gs[2]) | ((uint32_t)(uint16_t)f2bf(gs[3]) << 16);
  };

  __syncthreads();   // Wh + x[0] resident (vmcnt drained before s_barrier)

  // ---- prologue: produce gx[0] ----
  uint2 gx_cur, gx_nxt;
  produce(gx_cur);
  __syncthreads();   // all production ds_reads of x[0] retired -> XsC reusable

  for (int t = 0; t < S_LEN; ++t) {
    // stage x[t+1] now; drained by this step's drain-sync, consumed after it
    if (t + 1 < S_LEN) stage_x(t + 1);

    // ---- h matvec (swapped): acc[q] = gate q pre-activation of (b_ln, j0+jl) ----
    f32x4 acc0 = {}, acc1 = {};
    if (t) {
      const char* hs = hb_g + (size_t)(t - 1) * HSLOT + aoff;
      bf16x8 a[32];
#pragma unroll
      for (int ks = 0; ks < 32; ++ks)          // one parallel miss wave
        a[ks] = *(const bf16x8*)(hs + ks * 1024);
      __builtin_amdgcn_sched_barrier(0);
#pragma unroll
      for (int ks = 0; ks < 32; ++ks) {
        int wb = ks * 64 + bcol;
        bf16x8 w0 = *(const bf16x8*)(WhC + arow * 2048 + (wb ^ bswz));
        if (ks & 1) acc1 = __builtin_amdgcn_mfma_f32_16x16x32_bf16(w0, a[ks], acc1, 0, 0, 0);
        else        acc0 = __builtin_amdgcn_mfma_f32_16x16x32_bf16(w0, a[ks], acc0, 0, 0, 0);
      }
    }

    // ---- lane-local pointwise (gx from register ring, bias in f32) ----
    f32x4 ah = acc0 + acc1;
    float vi = ah[0] + bf2f((short)(gx_cur.x & 0xffff)) + bias_r[0];
    float vf = ah[1] + bf2f((short)(gx_cur.x >> 16))    + bias_r[1];
    float vg = ah[2] + bf2f((short)(gx_cur.y & 0xffff)) + bias_r[2];
    float vo = ah[3] + bf2f((short)(gx_cur.y >> 16))    + bias_r[3];
    float ig = sigm(vi), fg = sigm(vf), gg = tanh_fast(vg), og = sigm(vo);
    c_reg = fg * c_reg + ig * gg;
    float hn = og * tanh_fast(c_reg);

    // ---- publish h (write-through, 2 B) + out store (cached) ----
    if (t != S_LEN - 1)
      astore16(h_me + (size_t)t * HSLOT, (uint16_t)f2bf(hn));
    out_me[(size_t)t * NB * NH] = hn;
    if (t == S_LEN - 1) {
      float* oh = out + (size_t)S_LEN * NB * NH;
      size_t ci = (size_t)(grp * BPG + b_ln) * NH + j0 + jl;
      oh[ci] = hn;                        // final h
      oh[(size_t)NB * NH + ci] = c_reg;   // final c
    }

    if (t != S_LEN - 1) {
      __syncthreads();   // FULL drain: h + out stores acked; x[t+1] gloads landed
      const unsigned want = (unsigned)(t + 1);
      if (tid == 0) astore32((void*)(flags_g + wq * FLAGSTRIDE), want);

      // production for t+1, hidden in the poll shadow (reads XsC = x[t+1])
      produce(gx_nxt);

      if (wave == 0) {
        uint32_t v = aload32(fpoll);
        while (!__all(v >= want)) {
          __builtin_amdgcn_s_sleep(1);
          v = aload32(fpoll);
        }
      }
      __syncthreads();   // release: h slot t visible; XsC reads retired (lgkm drain)
      gx_cur = gx_nxt;
    }
  }
}

// ---------------- launch ----------------

extern "C" void kernel_launch(void* const* d_in, const int* in_sizes, int n_in,
                              void* d_out, int out_size, void* d_ws, size_t ws_size,
                              hipStream_t stream) {
  const float* x   = (const float*)d_in[0];
  const float* wxi = (const float*)d_in[1];
  const float* bxi = (const float*)d_in[2];
  const float* whi = (const float*)d_in[3];
  const float* bhi = (const float*)d_in[4];
  const float* bi  = (const float*)d_in[5];
  const float* wxf = (const float*)d_in[6];
  const float* bxf = (const float*)d_in[7];
  const float* whf = (const float*)d_in[8];
  const float* bhf = (const float*)d_in[9];
  const float* bf  = (const float*)d_in[10];
  const float* wxc = (const float*)d_in[11];
  const float* bxc = (const float*)d_in[12];
  const float* whc = (const float*)d_in[13];
  const float* bhc = (const float*)d_in[14];
  const float* bc  = (const float*)d_in[15];
  const float* wxo = (const float*)d_in[16];
  const float* bxo = (const float*)d_in[17];
  const float* who = (const float*)d_in[18];
  const float* bho = (const float*)d_in[19];
  const float* bo  = (const float*)d_in[20];

  char* ws = (char*)d_ws;
  const size_t SB = (size_t)S_LEN * NB;
  size_t off = 0;
  short* xbf   = (short*)(ws + off); off += SB * NI * 2;          // 67 MB (LIVE all run)
  short* wxcat = (short*)(ws + off); off += (size_t)NR * NI * 2;  // 8 MB
  short* whcat = (short*)(ws + off); off += (size_t)NR * NH * 2;  // 8 MB
  float* bias  = (float*)(ws + off); off += NR * 4;
  unsigned int* flags = (unsigned int*)(ws + off); off += NGRP * WPG * FLAGSTRIDE * 4;
  char* hb     = ws + off; off += (size_t)NGRP * S_LEN * HSLOT;   // 69 MB
  (void)ws_size; (void)in_sizes; (void)n_in; (void)out_size;

  float* out = (float*)d_out;

  (void)hipFuncSetAttribute((const void*)lstm_persist,
                            hipFuncAttributeMaxDynamicSharedMemorySize, LDS_BYTES);

  k_convert_x<<<(int)(SB * NI / 4 / 256), 256, 0, stream>>>(x, xbf);
  WPtrs wp = {wxi, wxf, wxc, wxo, whi, whf, whc, who};
  k_pack_w<<<(NR * NI / 4) / 256, 256, 0, stream>>>(wp, wxcat, whcat);
  BPtrs bp = {bxi, bhi, bi, bxf, bhf, bf, bxc, bhc, bc, bxo, bho, bo};
  k_init<<<NR / 256, 256, 0, stream>>>(bp, bias, flags);

  lstm_persist<<<NGRP * WPG, 256, LDS_BYTES, stream>>>(xbf, wxcat, whcat, bias,
                                                       hb, flags, out);
}

// Round 15
// 2394.566 us; speedup vs baseline: 1.7139x; 1.0030x over previous
//
#include <hip/hip_runtime.h>
#include <cstdint>
#include <cstddef>

#define S_LEN 512
#define NB    64
#define NI    1024
#define NH    1024
#define NR    4096   // 4 gates * NH, interleaved r = j*4 + g  (g: 0=i,1=f,2=c,3=o)
#define NGRP  4      // independent batch groups (16 batches each)
#define WPG   64     // WGs per group; each WG owns 64 weight rows = 16 j
#define BPG   16     // batches per group
#define HSLOT 33792  // per-step h slot: [wq=64][b=16][jl=16] bf16 (32 KB) + 1 KB pad
#define FLAGSTRIDE 16   // dwords between barrier flags (64 B)

typedef short bf16x8 __attribute__((ext_vector_type(8)));
typedef float f32x4  __attribute__((ext_vector_type(4)));

__device__ __forceinline__ short f2bf(float f) {
  uint32_t u = __float_as_uint(f);
  u += 0x7fff + ((u >> 16) & 1);          // RNE
  return (short)(u >> 16);
}
__device__ __forceinline__ float bf2f(short s) {
  return __uint_as_float(((uint32_t)(uint16_t)s) << 16);
}
__device__ __forceinline__ void gload16(const void* g, void* l) {
  __builtin_amdgcn_global_load_lds((const __attribute__((address_space(1))) void*)g,
                                   (__attribute__((address_space(3))) void*)l, 16, 0, 0);
}
__device__ __forceinline__ float sigm(float x) { return 1.0f / (1.0f + __expf(-x)); }
__device__ __forceinline__ float tanh_fast(float x) {
  return 2.0f / (1.0f + __expf(-2.0f * x)) - 1.0f;
}

// fabric write-through / uncached read (no fences needed; r3-r12 proven)
__device__ __forceinline__ void astore32(void* p, uint32_t v) {
  __hip_atomic_store((uint32_t*)p, v, __ATOMIC_RELAXED, __HIP_MEMORY_SCOPE_AGENT);
}
__device__ __forceinline__ void astore16(void* p, uint16_t v) {
  __hip_atomic_store((uint16_t*)p, v, __ATOMIC_RELAXED, __HIP_MEMORY_SCOPE_AGENT);
}
__device__ __forceinline__ uint32_t aload32(const void* p) {
  return __hip_atomic_load((const uint32_t*)p, __ATOMIC_RELAXED, __HIP_MEMORY_SCOPE_AGENT);
}

// ---------------- prep kernels ----------------

__global__ __launch_bounds__(256) void k_convert_x(const float* __restrict__ x,
                                                   short* __restrict__ xbf) {
  int tid = blockIdx.x * 256 + threadIdx.x;        // exactly SB*NI/4 threads
  float4 v = ((const float4*)x)[tid];
  short4 o;
  o.x = f2bf(v.x); o.y = f2bf(v.y); o.z = f2bf(v.z); o.w = f2bf(v.w);
  ((short4*)xbf)[tid] = o;
}

struct WPtrs { const float *xi, *xf, *xc, *xo, *hi, *hf, *hc, *ho; };

__global__ __launch_bounds__(256) void k_pack_w(WPtrs w, short* __restrict__ wxcat,
                                                short* __restrict__ whcat) {
  int tid  = blockIdx.x * 256 + threadIdx.x;       // NR*NI/4 threads
  int flat = tid * 4;
  int r = flat >> 10, k = flat & 1023;
  int j = r >> 2, g = r & 3;
  const float* px = (g == 0) ? w.xi : (g == 1) ? w.xf : (g == 2) ? w.xc : w.xo;
  const float* ph = (g == 0) ? w.hi : (g == 1) ? w.hf : (g == 2) ? w.hc : w.ho;
  float4 vx = *(const float4*)(px + j * 1024 + k);
  float4 vh = *(const float4*)(ph + j * 1024 + k);
  short4 ox, oh;
  ox.x = f2bf(vx.x); ox.y = f2bf(vx.y); ox.z = f2bf(vx.z); ox.w = f2bf(vx.w);
  oh.x = f2bf(vh.x); oh.y = f2bf(vh.y); oh.z = f2bf(vh.z); oh.w = f2bf(vh.w);
  *(short4*)(wxcat + flat) = ox;
  *(short4*)(whcat + flat) = oh;
}

struct BPtrs { const float *xi,*hi,*i_, *xf,*hf,*f_, *xc,*hc,*c_, *xo,*ho,*o_; };

__global__ __launch_bounds__(256) void k_init(BPtrs p, float* __restrict__ bias,
                                              unsigned int* __restrict__ flags) {
  int tid = blockIdx.x * 256 + threadIdx.x;        // NR = 4096 threads
  flags[tid] = 0;                                  // 4 grp x 64 wg x 16 = 4096 flags
  int j = tid >> 2, g = tid & 3;
  const float* bx = (g == 0) ? p.xi : (g == 1) ? p.xf : (g == 2) ? p.xc : p.xo;
  const float* bh = (g == 0) ? p.hi : (g == 1) ? p.hf : (g == 2) ? p.hc : p.ho;
  const float* bb = (g == 0) ? p.i_ : (g == 1) ? p.f_ : (g == 2) ? p.c_ : p.o_;
  bias[tid] = bx[j] + bh[j] + bb[j];
}

// ---------------- fused persistent kernel: recurrence + in-LDS-fed gx production ------
// Identical to round 14 EXCEPT stage_x(t+1) is issued AFTER the h-fragment
// loads (fenced with sched_barrier both sides): in-order vmcnt retirement
// means waiting for a[] no longer transitively waits for stage_x's HBM
// misses (r14's +1.7 us/step stall). stage_x still lands well before the
// drain-sync that fences its consumption — fencing structure unchanged.
//
// LDS: [0,131072) Wh 64r x 1024k bf16 (2048-B rows, XOR-swz);
//      [131072,163840) xstage 16b x 1024k bf16 (2048-B rows, XOR-swz).
#define LDS_BYTES 163840
#define XS_OFF    131072

__global__ __launch_bounds__(256, 1) void lstm_persist(
    const short* __restrict__ xbf,  // [S][64][1024] bf16
    const short* __restrict__ wx,   // [4096][1024] gate-interleaved
    const short* __restrict__ wh,   // [4096][1024]
    const float* __restrict__ bias, // [4096]
    char* __restrict__ hb,          // rotating h slots: [grp][S][HSLOT]
    unsigned int* __restrict__ flags, // [NGRP][WPG*FLAGSTRIDE]
    float* __restrict__ out) {
  extern __shared__ __align__(16) char lds[];
  char* WhC = lds;
  char* XsC = lds + XS_OFF;

  const int tid = threadIdx.x, wave = tid >> 6, lane = tid & 63;
  const int grp = blockIdx.x & 3;
  const int wq  = blockIdx.x >> 2;
  const int r0  = wq * 64;          // first weight row
  const int j0  = wq * 16;          // first hidden unit
  const char* whB = (const char*)(wh + (size_t)r0 * NH);
  char* hb_g = hb + (size_t)grp * S_LEN * HSLOT;
  unsigned int* flags_g = flags + grp * WPG * FLAGSTRIDE;

  // x tile base for this group (bytes); tile t' starts at xgB + t'*NB*NI*2
  const char* xgB = (const char*)(xbf + (size_t)grp * BPG * NI);

  // stage x[t'] tile into XsC: 8 gload16/thread, pre-swizzled source (rule #21)
  auto stage_x = [&](int tp) {
    const char* src = xgB + (size_t)tp * NB * NI * 2;
#pragma unroll
    for (int p = 0; p < 8; ++p) {
      int L = p * 4096 + tid * 16;
      int row = L >> 11, kb = L & 2047;
      gload16(src + (size_t)row * 2048 + (kb ^ ((row & 7) << 4)), XsC + L);
    }
  };

  // ---- stage Wh into LDS (64 rows x 2 KB), pre-swizzled source ----
#pragma unroll
  for (int p = 0; p < 32; ++p) {
    int L = p * 4096 + tid * 16;
    int row = L >> 11, kb = L & 2047;
    gload16(whB + (size_t)row * 2048 + (kb ^ ((row & 7) << 4)), lds + L);
  }
  stage_x(0);   // x[0] for the prologue production

  // lane identity (r11/r13-verified): batch b_ln, unit jl; acc[q] = gate q
  const int b_ln = lane & 15;
  const int jl   = wave * 4 + (lane >> 4);
  const int arow = wave * 16 + (lane & 15);   // A-operand row (both GEMMs)
  float c_reg = 0.f;

  // Wx rows pinned in registers (r13-verified mapping)
  bf16x8 wxr[32];
  {
    const short* wxp = wx + (size_t)(r0 + arow) * NI + (lane >> 4) * 8;
#pragma unroll
    for (int ks = 0; ks < 32; ++ks)
      wxr[ks] = *(const bf16x8*)(wxp + ks * 32);
  }

  // h (B-operand) fragment offset into [wq_k][b][jl] slot layout (r10-verified)
  const int aoff = (lane >> 5) * 512 + (lane & 15) * 32 + ((lane >> 4) & 1) * 16;
  // Wh (A-operand) LDS fragment
  const int bswz = (arow & 7) << 4;
  const int bcol = (lane >> 4) * 16;
  // x (B-operand) LDS fragment: row = lane&15 (2048-B rows, same swz as Wh)
  const int xrow = lane & 15;
  const int xswz = (xrow & 7) << 4;

  const f32x4 bias_r = *(const f32x4*)(bias + (j0 + jl) * 4);

  const unsigned int* fpoll = flags_g + lane * FLAGSTRIDE;
  char*  h_me   = hb_g + wq * 512 + b_ln * 32 + jl * 2;
  float* out_me = out + (size_t)(grp * BPG + b_ln) * NH + j0 + jl;

  // production quantum: gx tile from XsC (swizzled ds_reads) x wxr -> 2 dwords
  auto produce = [&](uint2& dst) {
    f32x4 g0 = {}, g1 = {};
#pragma unroll
    for (int ks = 0; ks < 32; ++ks) {
      int xb_off = ks * 64 + bcol;
      bf16x8 xb = *(const bf16x8*)(XsC + xrow * 2048 + (xb_off ^ xswz));
      if (ks & 1) g1 = __builtin_amdgcn_mfma_f32_16x16x32_bf16(wxr[ks], xb, g1, 0, 0, 0);
      else        g0 = __builtin_amdgcn_mfma_f32_16x16x32_bf16(wxr[ks], xb, g0, 0, 0, 0);
    }
    f32x4 gs = g0 + g1;
    dst.x = (uint32_t)(uint16_t)f2bf(gs[0]) | ((uint32_t)(uint16_t)f2bf(gs[1]) << 16);
    dst.y = (uint32_t)(uint16_t)f2bf(gs[2]) | ((uint32_t)(uint16_t)f2bf(gs[3]) << 16);
  };

  __syncthreads();   // Wh + x[0] resident (vmcnt drained before s_barrier)

  // ---- prologue: produce gx[0] ----
  uint2 gx_cur, gx_nxt;
  produce(gx_cur);
  __syncthreads();   // all production ds_reads of x[0] retired -> XsC reusable

  for (int t = 0; t < S_LEN; ++t) {
    // ---- h matvec (swapped): acc[q] = gate q pre-activation of (b_ln, j0+jl) ----
    f32x4 acc0 = {}, acc1 = {};
    if (t) {
      const char* hs = hb_g + (size_t)(t - 1) * HSLOT + aoff;
      bf16x8 a[32];
#pragma unroll
      for (int ks = 0; ks < 32; ++ks)          // one parallel miss wave
        a[ks] = *(const bf16x8*)(hs + ks * 1024);
      __builtin_amdgcn_sched_barrier(0);
      // stage x[t+1] AFTER the h loads: younger in the in-order vmcnt queue,
      // so consuming a[] never waits on stage_x's HBM misses (r14's stall).
      // Still drained by this step's drain-sync, consumed after it.
      if (t + 1 < S_LEN) stage_x(t + 1);
      __builtin_amdgcn_sched_barrier(0);
#pragma unroll
      for (int ks = 0; ks < 32; ++ks) {
        int wb = ks * 64 + bcol;
        bf16x8 w0 = *(const bf16x8*)(WhC + arow * 2048 + (wb ^ bswz));
        if (ks & 1) acc1 = __builtin_amdgcn_mfma_f32_16x16x32_bf16(w0, a[ks], acc1, 0, 0, 0);
        else        acc0 = __builtin_amdgcn_mfma_f32_16x16x32_bf16(w0, a[ks], acc0, 0, 0, 0);
      }
    } else {
      stage_x(1);   // t=0: no matvec; issue x[1] staging immediately
    }

    // ---- lane-local pointwise (gx from register ring, bias in f32) ----
    f32x4 ah = acc0 + acc1;
    float vi = ah[0] + bf2f((short)(gx_cur.x & 0xffff)) + bias_r[0];
    float vf = ah[1] + bf2f((short)(gx_cur.x >> 16))    + bias_r[1];
    float vg = ah[2] + bf2f((short)(gx_cur.y & 0xffff)) + bias_r[2];
    float vo = ah[3] + bf2f((short)(gx_cur.y >> 16))    + bias_r[3];
    float ig = sigm(vi), fg = sigm(vf), gg = tanh_fast(vg), og = sigm(vo);
    c_reg = fg * c_reg + ig * gg;
    float hn = og * tanh_fast(c_reg);

    // ---- publish h (write-through, 2 B) + out store (cached) ----
    if (t != S_LEN - 1)
      astore16(h_me + (size_t)t * HSLOT, (uint16_t)f2bf(hn));
    out_me[(size_t)t * NB * NH] = hn;
    if (t == S_LEN - 1) {
      float* oh = out + (size_t)S_LEN * NB * NH;
      size_t ci = (size_t)(grp * BPG + b_ln) * NH + j0 + jl;
      oh[ci] = hn;                        // final h
      oh[(size_t)NB * NH + ci] = c_reg;   // final c
    }

    if (t != S_LEN - 1) {
      __syncthreads();   // FULL drain: h + out stores acked; x[t+1] gloads landed
      const unsigned want = (unsigned)(t + 1);
      if (tid == 0) astore32((void*)(flags_g + wq * FLAGSTRIDE), want);

      // production for t+1, hidden in the poll shadow (reads XsC = x[t+1])
      produce(gx_nxt);

      if (wave == 0) {
        uint32_t v = aload32(fpoll);
        while (!__all(v >= want)) {
          __builtin_amdgcn_s_sleep(1);
          v = aload32(fpoll);
        }
      }
      __syncthreads();   // release: h slot t visible; XsC reads retired (lgkm drain)
      gx_cur = gx_nxt;
    }
  }
}

// ---------------- launch ----------------

extern "C" void kernel_launch(void* const* d_in, const int* in_sizes, int n_in,
                              void* d_out, int out_size, void* d_ws, size_t ws_size,
                              hipStream_t stream) {
  const float* x   = (const float*)d_in[0];
  const float* wxi = (const float*)d_in[1];
  const float* bxi = (const float*)d_in[2];
  const float* whi = (const float*)d_in[3];
  const float* bhi = (const float*)d_in[4];
  const float* bi  = (const float*)d_in[5];
  const float* wxf = (const float*)d_in[6];
  const float* bxf = (const float*)d_in[7];
  const float* whf = (const float*)d_in[8];
  const float* bhf = (const float*)d_in[9];
  const float* bf  = (const float*)d_in[10];
  const float* wxc = (const float*)d_in[11];
  const float* bxc = (const float*)d_in[12];
  const float* whc = (const float*)d_in[13];
  const float* bhc = (const float*)d_in[14];
  const float* bc  = (const float*)d_in[15];
  const float* wxo = (const float*)d_in[16];
  const float* bxo = (const float*)d_in[17];
  const float* who = (const float*)d_in[18];
  const float* bho = (const float*)d_in[19];
  const float* bo  = (const float*)d_in[20];

  char* ws = (char*)d_ws;
  const size_t SB = (size_t)S_LEN * NB;
  size_t off = 0;
  short* xbf   = (short*)(ws + off); off += SB * NI * 2;          // 67 MB (LIVE all run)
  short* wxcat = (short*)(ws + off); off += (size_t)NR * NI * 2;  // 8 MB
  short* whcat = (short*)(ws + off); off += (size_t)NR * NH * 2;  // 8 MB
  float* bias  = (float*)(ws + off); off += NR * 4;
  unsigned int* flags = (unsigned int*)(ws + off); off += NGRP * WPG * FLAGSTRIDE * 4;
  char* hb     = ws + off; off += (size_t)NGRP * S_LEN * HSLOT;   // 69 MB
  (void)ws_size; (void)in_sizes; (void)n_in; (void)out_size;

  float* out = (float*)d_out;

  (void)hipFuncSetAttribute((const void*)lstm_persist,
                            hipFuncAttributeMaxDynamicSharedMemorySize, LDS_BYTES);

  k_convert_x<<<(int)(SB * NI / 4 / 256), 256, 0, stream>>>(x, xbf);
  WPtrs wp = {wxi, wxf, wxc, wxo, whi, whf, whc, who};
  k_pack_w<<<(NR * NI / 4) / 256, 256, 0, stream>>>(wp, wxcat, whcat);
  BPtrs bp = {bxi, bhi, bi, bxf, bhf, bf, bxc, bhc, bc, bxo, bho, bo};
  k_init<<<NR / 256, 256, 0, stream>>>(bp, bias, flags);

  lstm_persist<<<NGRP * WPG, 256, LDS_BYTES, stream>>>(xbf, wxcat, whcat, bias,
                                                       hb, flags, out);
}

// Round 16
// 2002.378 us; speedup vs baseline: 2.0496x; 1.1959x over previous
//
#include <hip/hip_runtime.h>
#include <cstdint>
#include <cstddef>

#define S_LEN 512
#define NB    64
#define NI    1024
#define NH    1024
#define NR    4096   // 4 gates * NH, interleaved r = j*4 + g  (g: 0=i,1=f,2=c,3=o)
#define NGRP  4      // independent batch groups (16 batches each)
#define WPG   64     // WGs per group; each WG owns 64 weight rows = 16 j
#define BPG   16     // batches per group
#define HSLOT 33792  // per-step h slot: [wq=64][b=16][jl=16] bf16 (32 KB) + 1 KB pad
#define FLAGSTRIDE 16   // dwords between barrier flags (64 B)

typedef short bf16x8 __attribute__((ext_vector_type(8)));
typedef float f32x4  __attribute__((ext_vector_type(4)));

__device__ __forceinline__ short f2bf(float f) {
  uint32_t u = __float_as_uint(f);
  u += 0x7fff + ((u >> 16) & 1);          // RNE
  return (short)(u >> 16);
}
__device__ __forceinline__ float bf2f(short s) {
  return __uint_as_float(((uint32_t)(uint16_t)s) << 16);
}
__device__ __forceinline__ void gload16(const void* g, void* l) {
  __builtin_amdgcn_global_load_lds((const __attribute__((address_space(1))) void*)g,
                                   (__attribute__((address_space(3))) void*)l, 16, 0, 0);
}
__device__ __forceinline__ float sigm(float x) { return 1.0f / (1.0f + __expf(-x)); }
__device__ __forceinline__ float tanh_fast(float x) {
  return 2.0f / (1.0f + __expf(-2.0f * x)) - 1.0f;
}

// fabric write-through / uncached read (no fences needed; r3-r12 proven)
__device__ __forceinline__ void astore32(void* p, uint32_t v) {
  __hip_atomic_store((uint32_t*)p, v, __ATOMIC_RELAXED, __HIP_MEMORY_SCOPE_AGENT);
}
__device__ __forceinline__ uint32_t aload32(const void* p) {
  return __hip_atomic_load((const uint32_t*)p, __ATOMIC_RELAXED, __HIP_MEMORY_SCOPE_AGENT);
}

// ---------------- merged prep kernel (convert + pack + init, one launch) ----------------

struct PrepPtrs {
  const float *x;
  const float *wxi, *wxf, *wxc, *wxo;
  const float *whi, *whf, *whc, *who;
  const float *bxi, *bhi, *bi_, *bxf, *bhf, *bf_,
              *bxc, *bhc, *bc_, *bxo, *bho, *bo_;
};

#define CV_BLKS (S_LEN * NB * NI / 4 / 256)   // 32768
#define PK_BLKS (NR * NI / 4 / 256)           // 4096
#define IN_BLKS (NR / 256)                    // 16

__global__ __launch_bounds__(256) void k_prep(PrepPtrs p,
                                              short* __restrict__ xbf,
                                              short* __restrict__ wxcat,
                                              short* __restrict__ whcat,
                                              float* __restrict__ bias,
                                              unsigned int* __restrict__ flags) {
  const int bid = blockIdx.x;
  if (bid < CV_BLKS) {                         // ---- convert x -> bf16 ----
    int tid = bid * 256 + threadIdx.x;
    float4 v = ((const float4*)p.x)[tid];
    short4 o;
    o.x = f2bf(v.x); o.y = f2bf(v.y); o.z = f2bf(v.z); o.w = f2bf(v.w);
    ((short4*)xbf)[tid] = o;
  } else if (bid < CV_BLKS + PK_BLKS) {        // ---- pack W (gate-interleaved) ----
    int tid  = (bid - CV_BLKS) * 256 + threadIdx.x;
    int flat = tid * 4;
    int r = flat >> 10, k = flat & 1023;
    int j = r >> 2, g = r & 3;
    const float* px = (g == 0) ? p.wxi : (g == 1) ? p.wxf : (g == 2) ? p.wxc : p.wxo;
    const float* ph = (g == 0) ? p.whi : (g == 1) ? p.whf : (g == 2) ? p.whc : p.who;
    float4 vx = *(const float4*)(px + j * 1024 + k);
    float4 vh = *(const float4*)(ph + j * 1024 + k);
    short4 ox, oh;
    ox.x = f2bf(vx.x); ox.y = f2bf(vx.y); ox.z = f2bf(vx.z); ox.w = f2bf(vx.w);
    oh.x = f2bf(vh.x); oh.y = f2bf(vh.y); oh.z = f2bf(vh.z); oh.w = f2bf(vh.w);
    *(short4*)(wxcat + flat) = ox;
    *(short4*)(whcat + flat) = oh;
  } else {                                     // ---- bias fold + flag zero ----
    int tid = (bid - CV_BLKS - PK_BLKS) * 256 + threadIdx.x;   // [0, 4096)
    flags[tid] = 0;
    int j = tid >> 2, g = tid & 3;
    const float* bx = (g == 0) ? p.bxi : (g == 1) ? p.bxf : (g == 2) ? p.bxc : p.bxo;
    const float* bh = (g == 0) ? p.bhi : (g == 1) ? p.bhf : (g == 2) ? p.bhc : p.bho;
    const float* bb = (g == 0) ? p.bi_ : (g == 1) ? p.bf_ : (g == 2) ? p.bc_ : p.bo_;
    bias[tid] = bx[j] + bh[j] + bb[j];
  }
}

// ---------------- phase 1: gx = x @ Wx^T + bias (r12-verified) ----------------
// 256x256 tile, BK=64, 8 waves, double-buffered 128-KB LDS, counted vmcnt(8) +
// raw s_barrier, XOR-swizzled LDS (both-sides), setprio, XCD-chunked grid.
#define GX_LDS 131072

__global__ __launch_bounds__(512, 1) void gemm_x(const short* __restrict__ xbf,  // [32768][1024]
                                                 const short* __restrict__ wx,   // [4096][1024]
                                                 const float* __restrict__ bias, // [4096]
                                                 short* __restrict__ gx) {       // [32768][4096]
  extern __shared__ __align__(16) char lds[];   // A: [buf][half][128][64], B: +65536

  const int tid = threadIdx.x, wave = tid >> 6, lane = tid & 63;
  const int wm = wave >> 2, wn = wave & 3;      // wave grid 2M x 4N

  const int bid = blockIdx.x;                    // 2048 = 128 mt x 16 nt
  const int wg  = (bid & 7) * 256 + (bid >> 3);
  const int nt  = wg >> 7, mt = wg & 127;
  const int m0  = mt * 256, n0 = nt * 256;
  const char* aB = (const char*)xbf + (size_t)m0 * 2048;
  const char* bB = (const char*)wx + (size_t)n0 * 2048;

  auto stage = [&](int buf, int kt) {
#pragma unroll
    for (int s2 = 0; s2 < 4; ++s2) {            // op = s2>>1 (0=A,1=B), half = s2&1
      const int   op   = s2 >> 1, half = s2 & 1;
      const char* src0 = op ? bB : aB;
      char*       dst0 = lds + op * 65536 + buf * 32768 + half * 16384;
#pragma unroll
      for (int ss = 0; ss < 2; ++ss) {
        int L = ss * 8192 + tid * 16;
        int r128 = L >> 7, cb = L & 127;
        gload16(src0 + (size_t)(half * 128 + r128) * 2048 + kt * 128
                     + (cb ^ ((r128 & 7) << 4)),
                dst0 + L);
      }
    }
  };

  f32x4 acc[8][4] = {};
  const int colL = lane & 15;
  const int kchk = (lane >> 4) * 16;            // byte offset of lane's k-chunk

  stage(0, 0);
  int buf = 0;
  for (int kt = 0; kt < 16; ++kt) {
    if (kt < 15) stage(buf ^ 1, kt + 1);
    __builtin_amdgcn_sched_barrier(0);
    if (kt < 15) asm volatile("s_waitcnt vmcnt(8)" ::: "memory");
    else         asm volatile("s_waitcnt vmcnt(0)" ::: "memory");
    __builtin_amdgcn_s_barrier();               // buf complete for all waves
    __builtin_amdgcn_sched_barrier(0);

    const char* Ab = lds + buf * 32768 + wm * 16384;
    const char* Bb = lds + 65536 + buf * 32768;
    __builtin_amdgcn_s_setprio(1);
#pragma unroll
    for (int kk = 0; kk < 2; ++kk) {
      bf16x8 b[4], a[8];
#pragma unroll
      for (int jn = 0; jn < 4; ++jn) {
        int row = wn * 64 + jn * 16 + colL;
        int r128 = row & 127;
        b[jn] = *(const bf16x8*)(Bb + (row >> 7) * 16384 + r128 * 128
                                 + ((kk * 64 + kchk) ^ ((r128 & 7) << 4)));
      }
#pragma unroll
      for (int i = 0; i < 8; ++i) {
        int r128 = i * 16 + colL;
        a[i] = *(const bf16x8*)(Ab + r128 * 128
                                + ((kk * 64 + kchk) ^ ((r128 & 7) << 4)));
      }
#pragma unroll
      for (int i = 0; i < 8; ++i)
#pragma unroll
        for (int jn = 0; jn < 4; ++jn)
          acc[i][jn] = __builtin_amdgcn_mfma_f32_16x16x32_bf16(a[i], b[jn], acc[i][jn], 0, 0, 0);
    }
    __builtin_amdgcn_s_setprio(0);
    __builtin_amdgcn_sched_barrier(0);
    asm volatile("s_waitcnt lgkmcnt(0)" ::: "memory");
    __builtin_amdgcn_s_barrier();               // all reads of buf done -> restageable
    __builtin_amdgcn_sched_barrier(0);
    buf ^= 1;
  }

  // epilogue: bias + NT stores
#pragma unroll
  for (int jn = 0; jn < 4; ++jn) {
    int   n  = n0 + wn * 64 + jn * 16 + colL;
    float bv = bias[n];
#pragma unroll
    for (int i = 0; i < 8; ++i) {
#pragma unroll
      for (int q = 0; q < 4; ++q) {
        int m = m0 + wm * 128 + i * 16 + (lane >> 4) * 4 + q;
        __builtin_nontemporal_store((short)f2bf(acc[i][jn][q] + bv),
                                    &gx[(size_t)m * NR + n]);
      }
    }
  }
}

// ---------------- persistent recurrence kernel (r10/r12, proven best) ----------------
#define LDS_BYTES (131072 + 2 * 16 * 65 * 4)

__global__ __launch_bounds__(256, 1) void lstm_persist(
    const short* __restrict__ gx,   // [S][64][4096]
    const short* __restrict__ wh,   // [4096][1024]
    char* __restrict__ hb,          // rotating h slots: [grp][S][HSLOT]
    unsigned int* __restrict__ flags, // [NGRP][WPG*FLAGSTRIDE]
    float* __restrict__ out) {
  extern __shared__ __align__(16) char lds[];
  char* WhC = lds;
  float (*pre)[16][65] = (float(*)[16][65])(lds + 131072);

  const int tid = threadIdx.x, wave = tid >> 6, lane = tid & 63;
  const int grp = blockIdx.x & 3;
  const int wq  = blockIdx.x >> 2;
  const int r0  = wq * 64;          // first weight row
  const int j0  = wq * 16;          // first hidden unit
  const char* whB = (const char*)(wh + (size_t)r0 * NH);
  char* hb_g = hb + (size_t)grp * S_LEN * HSLOT;
  unsigned int* flags_g = flags + grp * WPG * FLAGSTRIDE;

  // ---- load Wh once (64 rows x 2 KB), swizzled via pre-swizzled source ----
#pragma unroll
  for (int p = 0; p < 32; ++p) {
    int L = p * 4096 + tid * 16;
    int row = L >> 11, kb = L & 2047;
    gload16(whB + (size_t)row * 2048 + (kb ^ ((row & 7) << 4)), lds + L);
  }

  // pointwise ownership (tid < 128): b in [0,16), jp in [0,8)
  const int b_pw = tid >> 3;
  const int jp   = tid & 7;
  float c_reg[2] = {0.f, 0.f};

  // A-fragment per-lane constant offset into the [wq][b][jl] slot layout
  const int aoff = (lane >> 5) * 512 + (lane & 15) * 32 + ((lane >> 4) & 1) * 16;
  // B (Wh) fragment: wave owns rows [wave*16, wave*16+16)
  const int br   = wave * 16 + (lane & 15);
  const int bswz = (br & 7) << 4;
  const int bcol = (lane >> 4) * 16;

  // barrier poll: wave 0, lane l watches group flag l
  const unsigned int* fpoll = flags_g + lane * FLAGSTRIDE;

  // this thread's gx address (r = j*4+g interleaved; 8 gates for j pair = 16 B)
  const short* gx_me = gx + ((size_t)grp * BPG + b_pw) * NR + j0 * 4 + jp * 8;

  __syncthreads();   // Wh resident (vmcnt drained by compiler before barrier)

  bf16x8 gx_cur = {}, gx_nxt = {};
  if (tid < 128) gx_cur = *(const bf16x8*)(gx_me);   // t = 0

  for (int t = 0; t < S_LEN; ++t) {
    f32x4 acc0 = {}, acc1 = {};
    if (t) {   // t=0: h=0 -> matvec contributes nothing
      const char* hs = hb_g + (size_t)(t - 1) * HSLOT + aoff;
      // all 32 cached 16-B loads issued as ONE wave (512-VGPR budget)
      bf16x8 a[32];
#pragma unroll
      for (int ks = 0; ks < 32; ++ks)
        a[ks] = *(const bf16x8*)(hs + ks * 1024);
      __builtin_amdgcn_sched_barrier(0);   // pin: loads issue before MFMA region
#pragma unroll
      for (int ks = 0; ks < 32; ++ks) {
        int wb = ks * 64 + bcol;
        bf16x8 b0 = *(const bf16x8*)(WhC + br * 2048 + (wb ^ bswz));
        if (ks & 1) acc1 = __builtin_amdgcn_mfma_f32_16x16x32_bf16(a[ks], b0, acc1, 0, 0, 0);
        else        acc0 = __builtin_amdgcn_mfma_f32_16x16x32_bf16(a[ks], b0, acc0, 0, 0, 0);
      }
    }

    // park pre-activations in LDS (parity buffer; MFMA C layout -> [b][r_local])
    const int par = t & 1;
    {
      f32x4 a0 = acc0 + acc1;
      const int colL = lane & 15;            // r within wave's 16-row block
      const int mB   = (lane >> 4) * 4;      // batch base
#pragma unroll
      for (int q = 0; q < 4; ++q)
        pre[par][mB + q][wave * 16 + colL] = a0[q];
    }
    __syncthreads();

    // pointwise: threads 0..127, one (b, j-pair) each; publish h write-through
    float hn2[2] = {0.f, 0.f};
    if (tid < 128) {
#pragma unroll
      for (int it = 0; it < 2; ++it) {
        int rl = (jp * 2 + it) * 4;          // local row of gate i
        float vi = pre[par][b_pw][rl + 0] + bf2f(gx_cur[it * 4 + 0]);
        float vf = pre[par][b_pw][rl + 1] + bf2f(gx_cur[it * 4 + 1]);
        float vg = pre[par][b_pw][rl + 2] + bf2f(gx_cur[it * 4 + 2]);
        float vo = pre[par][b_pw][rl + 3] + bf2f(gx_cur[it * 4 + 3]);
        float ig = sigm(vi), fg = sigm(vf), gg = tanh_fast(vg), og = sigm(vo);
        c_reg[it] = fg * c_reg[it] + ig * gg;
        hn2[it]   = og * tanh_fast(c_reg[it]);
      }
      if (t != S_LEN - 1) {
        // [wq][b][jl] slot layout: WG-contiguous 512-B block, exclusive lines
        char* hw = hb_g + (size_t)t * HSLOT + wq * 512 + b_pw * 32 + jp * 4;
        uint32_t hbits = (uint32_t)(uint16_t)f2bf(hn2[0]) |
                         ((uint32_t)(uint16_t)f2bf(hn2[1]) << 16);
        astore32(hw, hbits);
      }
    }

    if (t != S_LEN - 1) {
      __syncthreads();   // FULL drain: h stores acked at coherence point
      const unsigned want = (unsigned)(t + 1);
      if (tid == 0) astore32((void*)(flags_g + wq * FLAGSTRIDE), want);
    }

    // out stores AFTER the flag (cached; outside the h protocol)
    if (tid < 128) {
      float2 of = { hn2[0], hn2[1] };
      *(float2*)(out + ((size_t)t * NB + grp * BPG + b_pw) * NH + j0 + jp * 2) = of;
      if (t == S_LEN - 1) {
        float* oh = out + (size_t)S_LEN * NB * NH;
        int ci = (grp * BPG + b_pw) * NH + j0 + jp * 2;
        *(float2*)(oh + ci) = of;                                  // final h
        float2 cf = { c_reg[0], c_reg[1] };
        *(float2*)(oh + NB * NH + ci) = cf;                        // final c
      }
    }

    if (t != S_LEN - 1) {
      // gx prefetch for t+1 in the poll shadow
      if (tid < 128) {
        const int tp = (t + 1 < S_LEN) ? t + 1 : t;
        gx_nxt = *(const bf16x8*)(gx_me + (size_t)tp * NB * NR);
      }
      const unsigned want = (unsigned)(t + 1);
      if (wave == 0) {
        uint32_t v = aload32(fpoll);
        while (!__all(v >= want)) {
          __builtin_amdgcn_s_sleep(1);
          v = aload32(fpoll);
        }
      }
      __syncthreads();   // release: h slot t visible & fresh for everyone
      gx_cur = gx_nxt;
    }
  }
}

// ---------------- launch ----------------

extern "C" void kernel_launch(void* const* d_in, const int* in_sizes, int n_in,
                              void* d_out, int out_size, void* d_ws, size_t ws_size,
                              hipStream_t stream) {
  const float* x   = (const float*)d_in[0];
  const float* wxi = (const float*)d_in[1];
  const float* bxi = (const float*)d_in[2];
  const float* whi = (const float*)d_in[3];
  const float* bhi = (const float*)d_in[4];
  const float* bi  = (const float*)d_in[5];
  const float* wxf = (const float*)d_in[6];
  const float* bxf = (const float*)d_in[7];
  const float* whf = (const float*)d_in[8];
  const float* bhf = (const float*)d_in[9];
  const float* bf  = (const float*)d_in[10];
  const float* wxc = (const float*)d_in[11];
  const float* bxc = (const float*)d_in[12];
  const float* whc = (const float*)d_in[13];
  const float* bhc = (const float*)d_in[14];
  const float* bc  = (const float*)d_in[15];
  const float* wxo = (const float*)d_in[16];
  const float* bxo = (const float*)d_in[17];
  const float* who = (const float*)d_in[18];
  const float* bho = (const float*)d_in[19];
  const float* bo  = (const float*)d_in[20];

  char* ws = (char*)d_ws;
  const size_t SB = (size_t)S_LEN * NB;
  size_t off = 0;
  short* gxp   = (short*)(ws + off); off += SB * NR * 2;        // 268 MB
  short* xbf   = (short*)(ws + off); off += SB * NI * 2;        // 67 MB (dead after gemm_x)
  short* wxcat = (short*)(ws + off); off += (size_t)NR * NI * 2; // 8 MB (dead after gemm_x)
  short* whcat = (short*)(ws + off); off += (size_t)NR * NH * 2;
  float* bias  = (float*)(ws + off); off += NR * 4;
  unsigned int* flags = (unsigned int*)(ws + off); off += NGRP * WPG * FLAGSTRIDE * 4;
  (void)ws_size; (void)in_sizes; (void)n_in; (void)out_size;

  // rotating h slots ALIAS xbf+wxcat (dead once lstm_persist runs):
  // 4 grp x 512 slots x 33792 B = 69.2 MB <= 75.5 MB available.
  char* hb = (char*)xbf;

  float* out = (float*)d_out;

  (void)hipFuncSetAttribute((const void*)lstm_persist,
                            hipFuncAttributeMaxDynamicSharedMemorySize, LDS_BYTES);
  (void)hipFuncSetAttribute((const void*)gemm_x,
                            hipFuncAttributeMaxDynamicSharedMemorySize, GX_LDS);

  PrepPtrs pp = { x,
                  wxi, wxf, wxc, wxo,
                  whi, whf, whc, who,
                  bxi, bhi, bi, bxf, bhf, bf,
                  bxc, bhc, bc, bxo, bho, bo };
  k_prep<<<CV_BLKS + PK_BLKS + IN_BLKS, 256, 0, stream>>>(pp, xbf, wxcat, whcat,
                                                          bias, flags);

  gemm_x<<<(SB / 256) * (NR / 256), 512, GX_LDS, stream>>>(xbf, wxcat, bias, gxp);

  lstm_persist<<<NGRP * WPG, 256, LDS_BYTES, stream>>>(gxp, whcat, hb, flags, out);
}